// Round 8
// baseline (78.928 us; speedup 1.0000x reference)
//
#include <hip/hip_runtime.h>
#include <hip/hip_cooperative_groups.h>
#include <math.h>

namespace cg = cooperative_groups;

#define Bn   512
#define Tn   50
#define NAn  5
#define NCn  7
#define GHn  16
#define GWn  32
#define PC   (GHn*GWn)            // 512 cells per anchor plane
#define CELLS (NAn*PC)            // 2560 cells per batch
#define EXCL  0x8000

__device__ __constant__ float c_aw[NAn] = {1.0f, 2.0f, 3.5f, 5.0f, 8.0f};
__device__ __constant__ float c_ah[NAn] = {1.5f, 3.0f, 4.5f, 6.0f, 10.0f};

__device__ inline float sigm(float v) { return 1.0f / (1.0f + __expf(-v)); }
// -log(clip(1-sigmoid(v),1e-12)) == softplus(v) exactly for v < 27.6 (|v|<6 here)
__device__ inline float softplus(float v) {
  return fmaxf(v, 0.0f) + __logf(1.0f + __expf(-fabsf(v)));
}

__device__ inline float wred(float v) {
#pragma unroll
  for (int off = 32; off > 0; off >>= 1) v += __shfl_down(v, off, 64);
  return v;
}

// Single cooperative kernel: one block per batch; partials to private slots;
// grid-wide sync; block 0 reduces and finalizes. ONE graph node, no memset.
__global__ __launch_bounds__(256) void k_all(const float* __restrict__ x,
                                             const float* __restrict__ tg,
                                             float* __restrict__ part,
                                             float* __restrict__ out)
{
  const int b   = blockIdx.x;
  const int tid = threadIdx.x;

  // ---- issue conf loads FIRST (independent of LDS): 2 cells per anchor ----
  const float* xb = x + (size_t)b * (NAn * 14) * PC;
  float2 pc[NAn];
#pragma unroll
  for (int a = 0; a < NAn; ++a)
    pc[a] = *reinterpret_cast<const float2*>(xb + (a * 14 + 6) * PC + tid * 2);

  // ---- cooperative tg load into LDS (coalesced), also independent ----
  __shared__ float s_tg[Tn * 5];                  // 250 floats
  if (tid < Tn * 5) s_tg[tid] = tg[(size_t)b * (Tn * 5) + tid];

  __shared__ int   s_owner[CELLS];   // last-wins target tid per cell, -1 none
  __shared__ int   s_flags[CELLS];   // bits0..6 label set; bit15 mask|ignore
  __shared__ float s_tx[Tn], s_ty[Tn], s_tw[Tn], s_th[Tn];
  __shared__ float red6[4][6];

#pragma unroll
  for (int i = 0; i < CELLS / 256; ++i) { s_owner[tid + i * 256] = -1; s_flags[tid + i * 256] = 0; }
  __syncthreads();

  // ---- target phase: O(T) owner-map build from LDS-resident targets ----
  if (tid < Tn) {
    float c0 = s_tg[tid * 5 + 0], c1 = s_tg[tid * 5 + 1], c2 = s_tg[tid * 5 + 2];
    float c3 = s_tg[tid * 5 + 3], c4 = s_tg[tid * 5 + 4];
    bool valid = (c0 + c1 + c2 + c3 + c4) > 0.0f;
    float gx = c1 * (float)GWn, gy = c2 * (float)GHn;
    float gw = c3 * (float)GWn, gh = c4 * (float)GHn;
    float iou[NAn];
    int best = 0; float bestv = -1.0f;
#pragma unroll
    for (int q = 0; q < NAn; ++q) {
      float inter = fminf(gw, c_aw[q]) * fminf(gh, c_ah[q]);
      float u = inter / (gw * gh + c_aw[q] * c_ah[q] - inter + 1e-16f);
      iou[q] = u;
      if (u > bestv) { bestv = u; best = q; }     // first-max like argmax
    }
    int gi = (int)floorf(gx), gj = (int)floorf(gy);
    bool inb = (gi >= 0) && (gi < GWn) && (gj >= 0) && (gj < GHn); // mode='drop'
    s_tx[tid] = gx - floorf(gx);
    s_ty[tid] = gy - floorf(gy);
    s_tw[tid] = logf(gw / c_aw[best] + 1e-16f);
    s_th[tid] = logf(gh / c_ah[best] + 1e-16f);
    if (valid && inb) {
      int pcell = gj * GWn + gi;
      int cell  = best * PC + pcell;
      atomicMax(&s_owner[cell], tid);             // last-wins = max tid
      int lbl = (int)c0;
      int lb  = (lbl >= 0 && lbl < NCn) ? (1 << lbl) : 0;  // mode='drop'
      atomicOr(&s_flags[cell], lb | EXCL);
#pragma unroll
      for (int q = 0; q < NAn; ++q) if (iou[q] > 0.6f)
        atomicOr(&s_flags[q * PC + pcell], EXCL);
    }
  }
  __syncthreads();

  // ---- sweep: conf already in registers; 2 cells per anchor per thread ----
  float v_mse = 0.f, v_pc = 0.f, v_cls = 0.f, v_neg = 0.f, v_np = 0.f, v_nc = 0.f;
#pragma unroll
  for (int a = 0; a < NAn; ++a) {
    const float p6v[2] = {pc[a].x, pc[a].y};
    const float* pl = xb + a * 14 * PC;
#pragma unroll
    for (int u = 0; u < 2; ++u) {
      int pcell = tid * 2 + u;
      int cell  = a * PC + pcell;
      int flags = s_flags[cell];
      float p6  = p6v[u];
      if (!(flags & EXCL)) {                      // negative cell
        v_neg += softplus(p6);                    // == -log(1-sigm(p6))
        v_nc  += 1.0f;
      }
      int owner = s_owner[cell];
      if (owner >= 0) {                           // positive (masked) cell
        float p0 = pl[0 * PC + pcell];
        float p1 = pl[1 * PC + pcell];
        float p2 = pl[2 * PC + pcell];
        float p3 = pl[3 * PC + pcell];
        float dx = sigm(p0) - s_tx[owner];
        float dy = sigm(p1) - s_ty[owner];
        float dw = p2 - s_tw[owner];
        float dh = p3 - s_th[owner];
        v_mse += dx * dx + dy * dy + dw * dw + dh * dh;
        v_pc  += softplus(-p6);                   // == -log(sigm(p6))
        v_np  += 1.0f;
        int bits = flags & 0x7F;
        if (bits) {
          float s[NCn]; float m = -1e30f;
#pragma unroll
          for (int k = 0; k < NCn; ++k) {
            s[k] = sigm(pl[(size_t)(7 + k) * PC + pcell]);
            m = fmaxf(m, s[k]);
          }
          float ssum = 0.f;
#pragma unroll
          for (int k = 0; k < NCn; ++k) ssum += __expf(s[k] - m);
          float lse = m + __logf(ssum);
#pragma unroll
          for (int k = 0; k < NCn; ++k)
            if ((bits >> k) & 1) v_cls += lse - s[k];
        }
      }
    }
  }

  // ---- block reduction, plain column-major store ----
  float vals[6] = {v_mse, v_pc, v_cls, v_neg, v_np, v_nc};
  int wid = tid >> 6, lane = tid & 63;
#pragma unroll
  for (int k = 0; k < 6; ++k) {
    float r = wred(vals[k]);
    if (lane == 0) red6[wid][k] = r;
  }
  __syncthreads();
  if (tid < 6)
    part[(size_t)tid * Bn + b] = red6[0][tid] + red6[1][tid] + red6[2][tid] + red6[3][tid];

  // ---- grid-wide sync (cooperative launch), then block 0 finalizes ----
  cg::this_grid().sync();

  if (b == 0) {
    float v[6];
#pragma unroll
    for (int k = 0; k < 6; ++k)                    // coalesced column reads
      v[k] = part[(size_t)k * Bn + tid] + part[(size_t)k * Bn + tid + 256];
#pragma unroll
    for (int k = 0; k < 6; ++k) {
      float r = wred(v[k]);
      if (lane == 0) red6[wid][k] = r;
    }
    __syncthreads();
    if (tid == 0) {
      float a0 = red6[0][0] + red6[1][0] + red6[2][0] + red6[3][0];
      float a1 = red6[0][1] + red6[1][1] + red6[2][1] + red6[3][1];
      float a2 = red6[0][2] + red6[1][2] + red6[2][2] + red6[3][2];
      float a3 = red6[0][3] + red6[1][3] + red6[2][3] + red6[3][3];
      float a4 = red6[0][4] + red6[1][4] + red6[2][4] + red6[3][4];
      float a5 = red6[0][5] + red6[1][5] + red6[2][5] + red6[3][5];
      float npos = fmaxf(a4, 1.0f);
      float negc = fmaxf(a5, 1.0f);
      out[0] = a0 / npos + a3 / negc + a1 / npos + a2 / ((float)Bn * npos);
    }
  }
}

extern "C" void kernel_launch(void* const* d_in, const int* in_sizes, int n_in,
                              void* d_out, int out_size, void* d_ws, size_t ws_size,
                              hipStream_t stream)
{
  const float* x   = (const float*)d_in[0];
  const float* tg  = (const float*)d_in[1];
  float* part      = (float*)d_ws;                // 6*512 f32 = 12 KB
  float* out       = (float*)d_out;

  void* args[] = {(void*)&x, (void*)&tg, (void*)&part, (void*)&out};
  hipLaunchCooperativeKernel((const void*)k_all, dim3(Bn), dim3(256),
                             args, 0, stream);
}

// Round 9
// 47.281 us; speedup vs baseline: 1.6694x; 1.6694x over previous
//
#include <hip/hip_runtime.h>
#include <math.h>

#define Bn   512
#define Tn   50
#define NAn  5
#define NCn  7
#define PC   512                  // cells per anchor plane (16*32)
#define CELLS 2560                // cells per batch
#define SBLK 640                  // stream blocks: 640*256*2 float4 = all conf
#define NBLK (SBLK + Bn)          // 1152
#define TOTAL_CELLS (Bn*CELLS)    // 1310720
#define PART_T_OFF 1024           // float offset of target partials in ws
#define TICK_IDX 8192             // float-index of ticket (byte 32768)

__device__ __constant__ float c_aw[NAn] = {1.0f, 2.0f, 3.5f, 5.0f, 8.0f};
__device__ __constant__ float c_ah[NAn] = {1.5f, 3.0f, 4.5f, 6.0f, 10.0f};

__device__ inline float sigm(float v) { return 1.0f / (1.0f + __expf(-v)); }
// -log(clip(1-sigmoid(v),1e-12)) == softplus(v) exactly for v < 27.6 (|v|<6 here)
__device__ inline float softplus(float v) {
  return fmaxf(v, 0.0f) + __logf(1.0f + __expf(-fabsf(v)));
}
__device__ inline float wred(float v) {
#pragma unroll
  for (int off = 32; off > 0; off >>= 1) v += __shfl_down(v, off, 64);
  return v;
}
__device__ inline void astore(float* p, float v) {
  __hip_atomic_store(p, v, __ATOMIC_RELEASE, __HIP_MEMORY_SCOPE_AGENT);
}
__device__ inline float aload(const float* p) {
  return __hip_atomic_load(p, __ATOMIC_RELAXED, __HIP_MEMORY_SCOPE_AGENT);
}

// Single node. Blocks 0..639: stream full neg-BCE sum (no LDS, no barriers).
// Blocks 640..1151: per-batch target math via wave shuffles + 320B bitmap.
// Last block (modulo ticket, no memset needed) reduces 1152 partial slots.
__global__ __launch_bounds__(256) void k_all(const float* __restrict__ x,
                                             const float* __restrict__ tg,
                                             float* __restrict__ ws,
                                             int* __restrict__ tick,
                                             float* __restrict__ out)
{
  const int tid = threadIdx.x;
  const int blk = blockIdx.x;
  float v0 = 0.f, v1 = 0.f, v2 = 0.f, v3 = 0.f, v4 = 0.f, v5 = 0.f;
  // v0 mse, v1 pos-conf, v2 cls, v3 neg-sum, v4 n_pos, v5 neg-count-corr

  __shared__ float    s_tg[256];
  __shared__ unsigned s_un[80];      // union bitmap: mask | ignore cells
  __shared__ float    red6[4][6];
  __shared__ int      s_last;

  if (blk < SBLK) {
    // ---------------- stream role: all conf cells, branch-free ----------------
    const int gid = blk * 256 + tid;
#pragma unroll
    for (int k = 0; k < 2; ++k) {
      int idx = gid + k * (SBLK * 256);           // < 327680
      int plane = idx >> 7, rest = idx & 127;     // conf plane base = (14p+6)*512
      const float4 v = *reinterpret_cast<const float4*>(
          x + (size_t)(14 * plane + 6) * 512 + rest * 4);
      v3 += softplus(v.x) + softplus(v.y) + softplus(v.z) + softplus(v.w);
    }
  } else {
    // ---------------- target role: one small block per batch ----------------
    const int b = blk - SBLK;
    if (tid < Tn * 5) s_tg[tid] = tg[(size_t)b * (Tn * 5) + tid];
    if (tid < 80)     s_un[tid] = 0u;
    __syncthreads();

    if (tid < 64) {
      const int t = tid;
      float c0 = 0.f, c1 = 0.f, c2 = 0.f, c3 = 0.f, c4 = 0.f;
      if (t < Tn) {
        c0 = s_tg[t * 5]; c1 = s_tg[t * 5 + 1]; c2 = s_tg[t * 5 + 2];
        c3 = s_tg[t * 5 + 3]; c4 = s_tg[t * 5 + 4];
      }
      bool valid = (t < Tn) && ((c0 + c1 + c2 + c3 + c4) > 0.0f);
      float gx = c1 * 32.f, gy = c2 * 16.f, gw = c3 * 32.f, gh = c4 * 16.f;
      float iou[NAn]; int best = 0; float bestv = -1.f;
#pragma unroll
      for (int q = 0; q < NAn; ++q) {
        float inter = fminf(gw, c_aw[q]) * fminf(gh, c_ah[q]);
        float u = inter / (gw * gh + c_aw[q] * c_ah[q] - inter + 1e-16f);
        iou[q] = u;
        if (u > bestv) { bestv = u; best = q; }   // first-max like argmax
      }
      int gi = (int)floorf(gx), gj = (int)floorf(gy);
      bool inb = (gi >= 0) && (gi < 32) && (gj >= 0) && (gj < 16); // mode='drop'
      int lbl = (int)c0;
      int cellkey = (valid && inb) ? best * PC + gj * 32 + gi : -1 - t;
      bool lb_ok = (lbl >= 0 && lbl < NCn);
      int key2 = cellkey * 8 + (lb_ok ? lbl : 7);
      bool win = true;                            // last-wins: no later same cell
      bool pf  = (cellkey >= 0) && lb_ok;         // first (cell,label) occurrence
      for (int u = 0; u < Tn; ++u) {
        int cu = __shfl(cellkey, u, 64);
        int k2 = __shfl(key2,   u, 64);
        if (u > t && cu == cellkey) win = false;
        if (u < t && k2 == key2)    pf  = false;
      }
      if (cellkey >= 0) {
        atomicOr(&s_un[cellkey >> 5], 1u << (cellkey & 31));   // mask cell
        int pcell = gj * 32 + gi;
#pragma unroll
        for (int q = 0; q < NAn; ++q) if (iou[q] > 0.6f) {     // ignore cells
          int ic = q * PC + pcell;
          atomicOr(&s_un[ic >> 5], 1u << (ic & 31));
        }
        const size_t bb = ((size_t)b * 70 + best * 14) * PC + pcell;
        if (win) {
          float p0 = x[bb], p1 = x[bb + 512], p2 = x[bb + 1024];
          float p3 = x[bb + 1536], p6 = x[bb + 3072];
          float tx = gx - floorf(gx), ty = gy - floorf(gy);
          float tw = __logf(gw / c_aw[best] + 1e-16f);
          float th = __logf(gh / c_ah[best] + 1e-16f);
          float dx = sigm(p0) - tx, dy = sigm(p1) - ty;
          float dw = p2 - tw, dh = p3 - th;
          v0 += dx * dx + dy * dy + dw * dw + dh * dh;
          v1 += softplus(-p6);                    // -log(sigm(p6))
          v4 += 1.0f;
        }
        if (pf) {
          float s[NCn]; float m = -1e30f;
#pragma unroll
          for (int k = 0; k < NCn; ++k) {
            s[k] = sigm(x[bb + (size_t)(7 + k) * PC]);
            m = fmaxf(m, s[k]);
          }
          float ss = 0.f;
#pragma unroll
          for (int k = 0; k < NCn; ++k) ss += __expf(s[k] - m);
          v2 += (m + __logf(ss)) - s[lbl];        // -log_softmax[lbl]
        }
      }
    }
    __syncthreads();

    // correction: cancel excluded (mask|ignore) cells out of streamed full sum
    if (tid < 80) {
      unsigned bits = s_un[tid];
      while (bits) {
        int bit = __ffs(bits) - 1; bits &= bits - 1;
        int cell = tid * 32 + bit;
        int a = cell >> 9, rest = cell & 511;
        float p6 = x[((size_t)b * 70 + a * 14 + 6) * PC + rest];
        v3 -= softplus(p6);                       // bit-identical -> exact cancel
        v5 -= 1.0f;
      }
    }
  }

  // ---------------- block reduction + partial store ----------------
  int wid = tid >> 6, lane = tid & 63;
  float vals[6] = {v0, v1, v2, v3, v4, v5};
#pragma unroll
  for (int k = 0; k < 6; ++k) {
    float r = wred(vals[k]);
    if (lane == 0) red6[wid][k] = r;
  }
  __syncthreads();
  if (blk < SBLK) {
    if (tid == 0)
      astore(&ws[blk], red6[0][3] + red6[1][3] + red6[2][3] + red6[3][3]);
  } else {
    if (tid < 6)
      astore(&ws[PART_T_OFF + tid * Bn + (blk - SBLK)],
             red6[0][tid] + red6[1][tid] + red6[2][tid] + red6[3][tid]);
  }
  __syncthreads();

  // ---------------- modulo ticket: exactly one last block per call ----------------
  if (tid == 0) {
    __threadfence();
    unsigned o = (unsigned)atomicAdd(tick, 1);
    s_last = ((o % NBLK) == (NBLK - 1)) ? 1 : 0;
  }
  __syncthreads();

  if (s_last) {
    __threadfence();
    float sn = 0.f;
    for (int i = tid; i < SBLK; i += 256) sn += aload(&ws[i]);
    float sv[6];
#pragma unroll
    for (int k = 0; k < 6; ++k)
      sv[k] = aload(&ws[PART_T_OFF + k * Bn + tid]) +
              aload(&ws[PART_T_OFF + k * Bn + tid + 256]);
    sv[3] += sn;
#pragma unroll
    for (int k = 0; k < 6; ++k) {
      float r = wred(sv[k]);
      if (lane == 0) red6[wid][k] = r;
    }
    __syncthreads();
    if (tid == 0) {
      float a0 = red6[0][0] + red6[1][0] + red6[2][0] + red6[3][0];
      float a1 = red6[0][1] + red6[1][1] + red6[2][1] + red6[3][1];
      float a2 = red6[0][2] + red6[1][2] + red6[2][2] + red6[3][2];
      float a3 = red6[0][3] + red6[1][3] + red6[2][3] + red6[3][3];
      float a4 = red6[0][4] + red6[1][4] + red6[2][4] + red6[3][4];
      float a5 = red6[0][5] + red6[1][5] + red6[2][5] + red6[3][5];
      float npos = fmaxf(a4, 1.0f);
      float negc = fmaxf((float)TOTAL_CELLS + a5, 1.0f);
      out[0] = a0 / npos + a3 / negc + a1 / npos + a2 / ((float)Bn * npos);
    }
  }
}

extern "C" void kernel_launch(void* const* d_in, const int* in_sizes, int n_in,
                              void* d_out, int out_size, void* d_ws, size_t ws_size,
                              hipStream_t stream)
{
  const float* x  = (const float*)d_in[0];
  const float* tg = (const float*)d_in[1];
  float* ws   = (float*)d_ws;
  int*   tick = (int*)(ws + TICK_IDX);

  k_all<<<NBLK, 256, 0, stream>>>(x, tg, ws, tick, (float*)d_out);
}

// Round 10
// 16.505 us; speedup vs baseline: 4.7821x; 2.8646x over previous
//
#include <hip/hip_runtime.h>
#include <math.h>

#define Bn   512
#define Tn   50
#define NAn  5
#define NCn  7
#define PC   512                  // cells per anchor plane (16*32)
#define CELLS 2560                // cells per batch

__device__ __constant__ float c_aw[NAn] = {1.0f, 2.0f, 3.5f, 5.0f, 8.0f};
__device__ __constant__ float c_ah[NAn] = {1.5f, 3.0f, 4.5f, 6.0f, 10.0f};

__device__ inline float sigm(float v) { return 1.0f / (1.0f + __expf(-v)); }
// -log(clip(1-sigmoid(v),1e-12)) == softplus(v) exactly for v < 27.6 (|v|<6 here)
__device__ inline float softplus(float v) {
  return fmaxf(v, 0.0f) + __logf(1.0f + __expf(-fabsf(v)));
}
__device__ inline float wred(float v) {
#pragma unroll
  for (int off = 32; off > 0; off >>= 1) v += __shfl_down(v, off, 64);
  return v;
}

// One block per batch, 256 threads, ~1.7 KB LDS. No owner map: last-wins and
// (cell,label) dedup via 50 wave shuffles of one packed key; union bitmap only.
// Partials to private slots part[k*Bn+b]; tiny k_red finalizes.
__global__ __launch_bounds__(256) void k_batch(const float* __restrict__ x,
                                               const float* __restrict__ tg,
                                               float* __restrict__ part)
{
  const int b   = blockIdx.x;
  const int tid = threadIdx.x;
  const float* xb = x + (size_t)b * 70 * PC;

  // ---- hoist all hot loads: conf float2 per anchor + tg slice ----
  float2 pc[NAn];
#pragma unroll
  for (int a = 0; a < NAn; ++a)
    pc[a] = *reinterpret_cast<const float2*>(xb + (a * 14 + 6) * PC + tid * 2);

  __shared__ float    s_tg[256];
  __shared__ unsigned s_un[80];           // union bitmap: mask | ignore
  __shared__ float    red6[4][6];
  if (tid < Tn * 5) s_tg[tid] = tg[(size_t)b * (Tn * 5) + tid];
  if (tid < 80)     s_un[tid] = 0u;
  __syncthreads();

  float v0 = 0.f, v1 = 0.f, v2 = 0.f, v3 = 0.f, v4 = 0.f, v5 = 0.f;
  // v0 mse, v1 pos-conf, v2 cls, v3 neg-sum, v4 n_pos, v5 neg-count

  // ---- target phase: wave 0 only, shuffle dedup, winner lanes gather ----
  if (tid < 64) {
    const int t = tid;
    float c0 = 0.f, c1 = 0.f, c2 = 0.f, c3 = 0.f, c4 = 0.f;
    if (t < Tn) {
      c0 = s_tg[t * 5];     c1 = s_tg[t * 5 + 1]; c2 = s_tg[t * 5 + 2];
      c3 = s_tg[t * 5 + 3]; c4 = s_tg[t * 5 + 4];
    }
    bool valid = (t < Tn) && ((c0 + c1 + c2 + c3 + c4) > 0.0f);
    float gx = c1 * 32.f, gy = c2 * 16.f, gw = c3 * 32.f, gh = c4 * 16.f;
    float iou[NAn]; int best = 0; float bestv = -1.f;
#pragma unroll
    for (int q = 0; q < NAn; ++q) {
      float inter = fminf(gw, c_aw[q]) * fminf(gh, c_ah[q]);
      float u = inter / (gw * gh + c_aw[q] * c_ah[q] - inter + 1e-16f);
      iou[q] = u;
      if (u > bestv) { bestv = u; best = q; }     // first-max like argmax
    }
    int gi = (int)floorf(gx), gj = (int)floorf(gy);
    bool inb = (gi >= 0) && (gi < 32) && (gj >= 0) && (gj < 16); // mode='drop'
    int lbl = (int)c0;
    bool lb_ok = (lbl >= 0) && (lbl < NCn);
    int cellkey = (valid && inb) ? best * PC + gj * 32 + gi : -1 - t;
    int key = cellkey * 8 + (lb_ok ? lbl : 7);    // unique for invalid lanes
    bool win = (cellkey >= 0);                    // last-wins: no later same cell
    bool pf  = (cellkey >= 0) && lb_ok;           // first (cell,label) occurrence
    for (int u = 0; u < Tn; ++u) {
      int ku = __shfl(key, u, 64);
      if (u > t && (ku >> 3) == (key >> 3)) win = false;
      if (u < t && ku == key)               pf  = false;
    }
    if (cellkey >= 0) {
      atomicOr(&s_un[cellkey >> 5], 1u << (cellkey & 31));     // mask cell
      int pcell = gj * 32 + gi;
#pragma unroll
      for (int q = 0; q < NAn; ++q) if (iou[q] > 0.6f) {       // ignore cells
        int ic = q * PC + pcell;
        atomicOr(&s_un[ic >> 5], 1u << (ic & 31));
      }
      const size_t bb = (size_t)(best * 14) * PC + pcell;      // within batch
      if (win) {
        float p0 = xb[bb], p1 = xb[bb + 512], p2 = xb[bb + 1024];
        float p3 = xb[bb + 1536], p6 = xb[bb + 3072];
        float tx = gx - floorf(gx), ty = gy - floorf(gy);
        float tw = __logf(gw / c_aw[best] + 1e-16f);
        float th = __logf(gh / c_ah[best] + 1e-16f);
        float dx = sigm(p0) - tx, dy = sigm(p1) - ty;
        float dw = p2 - tw, dh = p3 - th;
        v0 += dx * dx + dy * dy + dw * dw + dh * dh;
        v1 += softplus(-p6);                      // -log(sigm(p6))
        v4 += 1.0f;
      }
      if (pf) {
        float s[NCn]; float m = -1e30f;
#pragma unroll
        for (int k = 0; k < NCn; ++k) {
          s[k] = sigm(xb[bb + (size_t)(7 + k) * PC]);
          m = fmaxf(m, s[k]);
        }
        float ss = 0.f;
#pragma unroll
        for (int k = 0; k < NCn; ++k) ss += __expf(s[k] - m);
        v2 += (m + __logf(ss)) - s[lbl];          // -log_softmax[lbl]
      }
    }
  }
  __syncthreads();

  // ---- sweep: conf already in registers; bitmap-gated negatives ----
#pragma unroll
  for (int a = 0; a < NAn; ++a) {
    const float p6v[2] = {pc[a].x, pc[a].y};
#pragma unroll
    for (int u = 0; u < 2; ++u) {
      int cell = a * PC + tid * 2 + u;
      if (!((s_un[cell >> 5] >> (cell & 31)) & 1u)) {
        v3 += softplus(p6v[u]);                   // -log(1-sigm(p6))
        v5 += 1.0f;
      }
    }
  }

  // ---- block reduction, column-major store to private slot ----
  float vals[6] = {v0, v1, v2, v3, v4, v5};
  int wid = tid >> 6, lane = tid & 63;
#pragma unroll
  for (int k = 0; k < 6; ++k) {
    float r = wred(vals[k]);
    if (lane == 0) red6[wid][k] = r;
  }
  __syncthreads();
  if (tid < 6)
    part[(size_t)tid * Bn + b] = red6[0][tid] + red6[1][tid] + red6[2][tid] + red6[3][tid];
}

__global__ __launch_bounds__(256) void k_red(const float* __restrict__ part,
                                             float* __restrict__ out)
{
  const int tid = threadIdx.x;
  float v[6];
#pragma unroll
  for (int k = 0; k < 6; ++k)                     // coalesced column reads
    v[k] = part[(size_t)k * Bn + tid] + part[(size_t)k * Bn + tid + 256];

  __shared__ float red6[4][6];
  int wid = tid >> 6, lane = tid & 63;
#pragma unroll
  for (int k = 0; k < 6; ++k) {
    float r = wred(v[k]);
    if (lane == 0) red6[wid][k] = r;
  }
  __syncthreads();
  if (tid == 0) {
    float a0 = red6[0][0] + red6[1][0] + red6[2][0] + red6[3][0];
    float a1 = red6[0][1] + red6[1][1] + red6[2][1] + red6[3][1];
    float a2 = red6[0][2] + red6[1][2] + red6[2][2] + red6[3][2];
    float a3 = red6[0][3] + red6[1][3] + red6[2][3] + red6[3][3];
    float a4 = red6[0][4] + red6[1][4] + red6[2][4] + red6[3][4];
    float a5 = red6[0][5] + red6[1][5] + red6[2][5] + red6[3][5];
    float npos = fmaxf(a4, 1.0f);
    float negc = fmaxf(a5, 1.0f);
    out[0] = a0 / npos + a3 / negc + a1 / npos + a2 / ((float)Bn * npos);
  }
}

extern "C" void kernel_launch(void* const* d_in, const int* in_sizes, int n_in,
                              void* d_out, int out_size, void* d_ws, size_t ws_size,
                              hipStream_t stream)
{
  const float* x  = (const float*)d_in[0];
  const float* tg = (const float*)d_in[1];
  float* part = (float*)d_ws;                     // 6*512 f32 = 12 KB

  k_batch<<<Bn, 256, 0, stream>>>(x, tg, part);
  k_red<<<1, 256, 0, stream>>>(part, (float*)d_out);
}

// Round 11
// 15.515 us; speedup vs baseline: 5.0872x; 1.0638x over previous
//
#include <hip/hip_runtime.h>
#include <math.h>

#define Bn   512
#define Tn   50
#define NAn  5
#define NCn  7
#define PC   512                  // cells per anchor plane (16*32)

__device__ __constant__ float c_aw[NAn] = {1.0f, 2.0f, 3.5f, 5.0f, 8.0f};
__device__ __constant__ float c_ah[NAn] = {1.5f, 3.0f, 4.5f, 6.0f, 10.0f};

__device__ inline float sigm(float v) { return 1.0f / (1.0f + __expf(-v)); }
// -log(clip(1-sigmoid(v),1e-12)) == softplus(v) exactly for |v| < 27.6 (|v|<6 here)
__device__ inline float softplus(float v) {
  return fmaxf(v, 0.0f) + __logf(1.0f + __expf(-fabsf(v)));
}
__device__ inline float wred(float v) {
#pragma unroll
  for (int off = 32; off > 0; off >>= 1) v += __shfl_down(v, off, 64);
  return v;
}

// One block per batch. Wave 0: direct tg loads + all target math + speculative
// positive-cell gathers issued PRE-barrier (latency hides under barrier+shfl
// dedup); waves 1-3 zero the union bitmap concurrently. Post-barrier: atomicOr
// + 50-shfl dedup + consume. Then 256-thread bitmap-gated conf sweep.
__global__ __launch_bounds__(256) void k_batch(const float* __restrict__ x,
                                               const float* __restrict__ tg,
                                               float* __restrict__ part)
{
  const int b   = blockIdx.x;
  const int tid = threadIdx.x;
  const int wid = tid >> 6, lane = tid & 63;
  const float* xb = x + (size_t)b * 70 * PC;

  // ---- conf loads first (fully coalesced, 2 cells per anchor per thread) ----
  float2 pc[NAn];
#pragma unroll
  for (int a = 0; a < NAn; ++a)
    pc[a] = *reinterpret_cast<const float2*>(xb + (a * 14 + 6) * PC + tid * 2);

  __shared__ unsigned s_un[80];          // union bitmap: mask | ignore
  __shared__ float    red6[4][6];

  float v0 = 0.f, v1 = 0.f, v2 = 0.f, v3 = 0.f, v4 = 0.f, v5 = 0.f;
  // v0 mse, v1 pos-conf, v2 cls, v3 neg-sum, v4 n_pos, v5 neg-count

  // ---- pre-barrier phase ----
  int   cellkey = -1, key = -1, best = 0, lbl = 0;
  float iou[NAn];
  float tx = 0.f, ty = 0.f, tw = 0.f, th = 0.f;
  float g0 = 0.f, g1 = 0.f, g2 = 0.f, g3 = 0.f, g6 = 0.f;
  float gc0 = 0.f, gc1 = 0.f, gc2 = 0.f, gc3 = 0.f, gc4 = 0.f, gc5 = 0.f, gc6 = 0.f;

  if (wid == 0) {
    const int t = lane;
    float c0 = 0.f, c1 = 0.f, c2 = 0.f, c3 = 0.f, c4 = 0.f;
    if (t < Tn) {                         // direct global reads, no LDS stage
      const float* tp = tg + (size_t)b * (Tn * 5) + t * 5;
      c0 = tp[0]; c1 = tp[1]; c2 = tp[2]; c3 = tp[3]; c4 = tp[4];
    }
    bool valid = (t < Tn) && ((c0 + c1 + c2 + c3 + c4) > 0.0f);
    float gx = c1 * 32.f, gy = c2 * 16.f, gw = c3 * 32.f, gh = c4 * 16.f;
    float bestv = -1.f;
#pragma unroll
    for (int q = 0; q < NAn; ++q) {
      float inter = fminf(gw, c_aw[q]) * fminf(gh, c_ah[q]);
      float u = inter / (gw * gh + c_aw[q] * c_ah[q] - inter + 1e-16f);
      iou[q] = u;
      if (u > bestv) { bestv = u; best = q; }   // first-max like argmax
    }
    int gi = (int)floorf(gx), gj = (int)floorf(gy);
    bool inb = (gi >= 0) && (gi < 32) && (gj >= 0) && (gj < 16); // mode='drop'
    lbl = (int)c0;
    bool lb_ok = (lbl >= 0) && (lbl < NCn);
    cellkey = (valid && inb) ? best * PC + gj * 32 + gi : -1 - t;
    key = cellkey * 8 + (lb_ok ? lbl : 7);
    tx = gx - floorf(gx); ty = gy - floorf(gy);
    tw = __logf(gw / c_aw[best] + 1e-16f);
    th = __logf(gh / c_ah[best] + 1e-16f);
    if (cellkey >= 0) {                   // speculative gathers: issue NOW,
      const size_t bb = (size_t)(best * 14) * PC + (cellkey & (PC - 1));
      g0  = xb[bb];          g1  = xb[bb + 512];   g2 = xb[bb + 1024];
      g3  = xb[bb + 1536];   g6  = xb[bb + 3072];
      gc0 = xb[bb + 3584];   gc1 = xb[bb + 4096];  gc2 = xb[bb + 4608];
      gc3 = xb[bb + 5120];   gc4 = xb[bb + 5632];  gc5 = xb[bb + 6144];
      gc6 = xb[bb + 6656];                // consumed only under win/pf later
    }
  } else {
    int z = tid - 64;                     // waves 1-3 zero the bitmap
    if (z < 80) s_un[z] = 0u;
  }
  __syncthreads();

  // ---- post-barrier: wave 0 scatters bits, dedups, consumes gathers ----
  if (wid == 0) {
    if (cellkey >= 0) {
      int pcell = cellkey & (PC - 1);
      atomicOr(&s_un[cellkey >> 5], 1u << (cellkey & 31));     // mask cell
#pragma unroll
      for (int q = 0; q < NAn; ++q) if (iou[q] > 0.6f) {       // ignore cells
        int ic = q * PC + pcell;
        atomicOr(&s_un[ic >> 5], 1u << (ic & 31));
      }
    }
    bool win = (cellkey >= 0);            // last-wins: no later same cell
    bool pf  = (cellkey >= 0) && ((key & 7) < 7);  // first (cell,label) pair
    const int t = lane;
    for (int u = 0; u < Tn; ++u) {
      int ku = __shfl(key, u, 64);
      if (u > t && (ku >> 3) == (key >> 3)) win = false;
      if (u < t && ku == key)               pf  = false;
    }
    if (win) {
      float dx = sigm(g0) - tx, dy = sigm(g1) - ty;
      float dw = g2 - tw, dh = g3 - th;
      v0 += dx * dx + dy * dy + dw * dw + dh * dh;
      v1 += softplus(-g6);                // -log(sigm(p6))
      v4 += 1.0f;
    }
    if (pf) {
      float s0 = sigm(gc0), s1 = sigm(gc1), s2 = sigm(gc2), s3 = sigm(gc3);
      float s4 = sigm(gc4), s5 = sigm(gc5), s6 = sigm(gc6);
      float m = fmaxf(fmaxf(fmaxf(s0, s1), fmaxf(s2, s3)),
                      fmaxf(fmaxf(s4, s5), s6));
      float ss = __expf(s0 - m) + __expf(s1 - m) + __expf(s2 - m) +
                 __expf(s3 - m) + __expf(s4 - m) + __expf(s5 - m) +
                 __expf(s6 - m);
      float sl = (lbl == 0) ? s0 : (lbl == 1) ? s1 : (lbl == 2) ? s2 :
                 (lbl == 3) ? s3 : (lbl == 4) ? s4 : (lbl == 5) ? s5 : s6;
      v2 += (m + __logf(ss)) - sl;        // -log_softmax[lbl], no scratch idx
    }
  }
  __syncthreads();

  // ---- sweep: conf in registers; bitmap-gated negatives ----
#pragma unroll
  for (int a = 0; a < NAn; ++a) {
    const float p6v[2] = {pc[a].x, pc[a].y};
#pragma unroll
    for (int u = 0; u < 2; ++u) {
      int cell = a * PC + tid * 2 + u;
      if (!((s_un[cell >> 5] >> (cell & 31)) & 1u)) {
        v3 += softplus(p6v[u]);           // -log(1-sigm(p6))
        v5 += 1.0f;
      }
    }
  }

  // ---- block reduction, column-major store to private slot ----
  float vals[6] = {v0, v1, v2, v3, v4, v5};
#pragma unroll
  for (int k = 0; k < 6; ++k) {
    float r = wred(vals[k]);
    if (lane == 0) red6[wid][k] = r;
  }
  __syncthreads();
  if (tid < 6)
    part[(size_t)tid * Bn + b] = red6[0][tid] + red6[1][tid] + red6[2][tid] + red6[3][tid];
}

// Single-wave finalize: no barrier, no LDS.
__global__ __launch_bounds__(64) void k_red(const float* __restrict__ part,
                                            float* __restrict__ out)
{
  const int lane = threadIdx.x;
  float a[6];
#pragma unroll
  for (int k = 0; k < 6; ++k) {
    const float* p = part + (size_t)k * Bn + lane * 8;
    float4 lo = *reinterpret_cast<const float4*>(p);
    float4 hi = *reinterpret_cast<const float4*>(p + 4);
    float s = ((lo.x + lo.y) + (lo.z + lo.w)) + ((hi.x + hi.y) + (hi.z + hi.w));
    a[k] = wred(s);
  }
  if (lane == 0) {
    float npos = fmaxf(a[4], 1.0f);
    float negc = fmaxf(a[5], 1.0f);
    out[0] = a[0] / npos + a[3] / negc + a[1] / npos + a[2] / ((float)Bn * npos);
  }
}

extern "C" void kernel_launch(void* const* d_in, const int* in_sizes, int n_in,
                              void* d_out, int out_size, void* d_ws, size_t ws_size,
                              hipStream_t stream)
{
  const float* x  = (const float*)d_in[0];
  const float* tg = (const float*)d_in[1];
  float* part = (float*)d_ws;                     // 6*512 f32 = 12 KB

  k_batch<<<Bn, 256, 0, stream>>>(x, tg, part);
  k_red<<<1, 64, 0, stream>>>(part, (float*)d_out);
}

// Round 12
// 14.923 us; speedup vs baseline: 5.2892x; 1.0397x over previous
//
#include <hip/hip_runtime.h>
#include <math.h>

#define Bn   512
#define Tn   50
#define NAn  5
#define NCn  7
#define PC   512                  // cells per anchor plane (16*32)

__device__ __constant__ float c_aw[NAn] = {1.0f, 2.0f, 3.5f, 5.0f, 8.0f};
__device__ __constant__ float c_ah[NAn] = {1.5f, 3.0f, 4.5f, 6.0f, 10.0f};

__device__ inline float sigm(float v) { return 1.0f / (1.0f + __expf(-v)); }
// -log(clip(1-sigmoid(v),1e-12)) == softplus(v) exactly for |v| < 27.6 (|v|<6 here)
__device__ inline float softplus(float v) {
  return fmaxf(v, 0.0f) + __logf(1.0f + __expf(-fabsf(v)));
}
__device__ inline float wred(float v) {
#pragma unroll
  for (int off = 32; off > 0; off >>= 1) v += __shfl_down(v, off, 64);
  return v;
}

// One block per batch. Wave 0: direct tg loads + target math + speculative
// gathers pre-barrier; waves 1-3 zero bitmap. Post-barrier: atomicOr + 50-shfl
// dedup + consume (wave 0 only -> v0,v1,v2,v4 reduced wave-0-only). All 256
// threads: bitmap-gated conf sweep (v3,v5 -> cross-wave reduce, 2 values).
__global__ __launch_bounds__(256) void k_batch(const float* __restrict__ x,
                                               const float* __restrict__ tg,
                                               float* __restrict__ part)
{
  const int b   = blockIdx.x;
  const int tid = threadIdx.x;
  const int wid = tid >> 6, lane = tid & 63;
  const float* xb = x + (size_t)b * 70 * PC;

  // ---- conf loads first (fully coalesced, 2 cells per anchor per thread) ----
  float2 pc[NAn];
#pragma unroll
  for (int a = 0; a < NAn; ++a)
    pc[a] = *reinterpret_cast<const float2*>(xb + (a * 14 + 6) * PC + tid * 2);

  __shared__ unsigned s_un[80];          // union bitmap: mask | ignore
  __shared__ float    red2[4][2];        // cross-wave partials for v3,v5 only

  float v0 = 0.f, v1 = 0.f, v2 = 0.f, v3 = 0.f, v4 = 0.f, v5 = 0.f;

  // ---- pre-barrier phase ----
  int   cellkey = -1, key = -1, best = 0, lbl = 0;
  float iou[NAn];
  float tx = 0.f, ty = 0.f, tw = 0.f, th = 0.f;
  float g0 = 0.f, g1 = 0.f, g2 = 0.f, g3 = 0.f, g6 = 0.f;
  float gc0 = 0.f, gc1 = 0.f, gc2 = 0.f, gc3 = 0.f, gc4 = 0.f, gc5 = 0.f, gc6 = 0.f;

  if (wid == 0) {
    const int t = lane;
    float c0 = 0.f, c1 = 0.f, c2 = 0.f, c3 = 0.f, c4 = 0.f;
    if (t < Tn) {                         // direct global reads, no LDS stage
      const float* tp = tg + (size_t)b * (Tn * 5) + t * 5;
      c0 = tp[0]; c1 = tp[1]; c2 = tp[2]; c3 = tp[3]; c4 = tp[4];
    }
    bool valid = (t < Tn) && ((c0 + c1 + c2 + c3 + c4) > 0.0f);
    float gx = c1 * 32.f, gy = c2 * 16.f, gw = c3 * 32.f, gh = c4 * 16.f;
    float bestv = -1.f;
#pragma unroll
    for (int q = 0; q < NAn; ++q) {
      float inter = fminf(gw, c_aw[q]) * fminf(gh, c_ah[q]);
      float u = inter / (gw * gh + c_aw[q] * c_ah[q] - inter + 1e-16f);
      iou[q] = u;
      if (u > bestv) { bestv = u; best = q; }   // first-max like argmax
    }
    int gi = (int)floorf(gx), gj = (int)floorf(gy);
    bool inb = (gi >= 0) && (gi < 32) && (gj >= 0) && (gj < 16); // mode='drop'
    lbl = (int)c0;
    bool lb_ok = (lbl >= 0) && (lbl < NCn);
    cellkey = (valid && inb) ? best * PC + gj * 32 + gi : -1 - t;
    key = cellkey * 8 + (lb_ok ? lbl : 7);
    tx = gx - floorf(gx); ty = gy - floorf(gy);
    tw = __logf(gw / c_aw[best] + 1e-16f);
    th = __logf(gh / c_ah[best] + 1e-16f);
    if (cellkey >= 0) {                   // speculative gathers: issue NOW
      const size_t bb = (size_t)(best * 14) * PC + (cellkey & (PC - 1));
      g0  = xb[bb];          g1  = xb[bb + 512];   g2 = xb[bb + 1024];
      g3  = xb[bb + 1536];   g6  = xb[bb + 3072];
      gc0 = xb[bb + 3584];   gc1 = xb[bb + 4096];  gc2 = xb[bb + 4608];
      gc3 = xb[bb + 5120];   gc4 = xb[bb + 5632];  gc5 = xb[bb + 6144];
      gc6 = xb[bb + 6656];                // consumed only under win/pf later
    }
  } else {
    int z = tid - 64;                     // waves 1-3 zero the bitmap
    if (z < 80) s_un[z] = 0u;
  }
  __syncthreads();

  // ---- post-barrier: wave 0 scatters bits, dedups, consumes gathers ----
  if (wid == 0) {
    if (cellkey >= 0) {
      int pcell = cellkey & (PC - 1);
      atomicOr(&s_un[cellkey >> 5], 1u << (cellkey & 31));     // mask cell
#pragma unroll
      for (int q = 0; q < NAn; ++q) if (iou[q] > 0.6f) {       // ignore cells
        int ic = q * PC + pcell;
        atomicOr(&s_un[ic >> 5], 1u << (ic & 31));
      }
    }
    bool win = (cellkey >= 0);            // last-wins: no later same cell
    bool pf  = (cellkey >= 0) && ((key & 7) < 7);  // first (cell,label) pair
    const int t = lane;
    for (int u = 0; u < Tn; ++u) {
      int ku = __shfl(key, u, 64);
      if (u > t && (ku >> 3) == (key >> 3)) win = false;
      if (u < t && ku == key)               pf  = false;
    }
    if (win) {
      float dx = sigm(g0) - tx, dy = sigm(g1) - ty;
      float dw = g2 - tw, dh = g3 - th;
      v0 += dx * dx + dy * dy + dw * dw + dh * dh;
      v1 += softplus(-g6);                // -log(sigm(p6))
      v4 += 1.0f;
    }
    if (pf) {
      float s0 = sigm(gc0), s1 = sigm(gc1), s2 = sigm(gc2), s3 = sigm(gc3);
      float s4 = sigm(gc4), s5 = sigm(gc5), s6 = sigm(gc6);
      float m = fmaxf(fmaxf(fmaxf(s0, s1), fmaxf(s2, s3)),
                      fmaxf(fmaxf(s4, s5), s6));
      float ss = __expf(s0 - m) + __expf(s1 - m) + __expf(s2 - m) +
                 __expf(s3 - m) + __expf(s4 - m) + __expf(s5 - m) +
                 __expf(s6 - m);
      float sl = (lbl == 0) ? s0 : (lbl == 1) ? s1 : (lbl == 2) ? s2 :
                 (lbl == 3) ? s3 : (lbl == 4) ? s4 : (lbl == 5) ? s5 : s6;
      v2 += (m + __logf(ss)) - sl;        // -log_softmax[lbl]
    }
  }
  __syncthreads();

  // ---- sweep: conf in registers; one hoisted bitmap word per anchor ----
#pragma unroll
  for (int a = 0; a < NAn; ++a) {
    unsigned wv = s_un[a * 16 + (tid >> 4)];   // both cells share this word
    int bit = (tid * 2) & 31;
    if (!((wv >> bit) & 1u))       { v3 += softplus(pc[a].x); v5 += 1.0f; }
    if (!((wv >> (bit + 1)) & 1u)) { v3 += softplus(pc[a].y); v5 += 1.0f; }
  }

  // ---- reductions: v3,v5 cross-wave; v0,v1,v2,v4 wave-0-only ----
  float r3 = wred(v3), r5 = wred(v5);
  if (lane == 0) { red2[wid][0] = r3; red2[wid][1] = r5; }
  if (wid == 0) {
    float r0 = wred(v0), r1 = wred(v1), r2 = wred(v2), r4 = wred(v4);
    if (lane == 0) {
      part[(size_t)0 * Bn + b] = r0;
      part[(size_t)1 * Bn + b] = r1;
      part[(size_t)2 * Bn + b] = r2;
      part[(size_t)4 * Bn + b] = r4;
    }
  }
  __syncthreads();
  if (tid == 0) {
    part[(size_t)3 * Bn + b] = red2[0][0] + red2[1][0] + red2[2][0] + red2[3][0];
    part[(size_t)5 * Bn + b] = red2[0][1] + red2[1][1] + red2[2][1] + red2[3][1];
  }
}

// Single-wave finalize: no barrier, no LDS.
__global__ __launch_bounds__(64) void k_red(const float* __restrict__ part,
                                            float* __restrict__ out)
{
  const int lane = threadIdx.x;
  float a[6];
#pragma unroll
  for (int k = 0; k < 6; ++k) {
    const float* p = part + (size_t)k * Bn + lane * 8;
    float4 lo = *reinterpret_cast<const float4*>(p);
    float4 hi = *reinterpret_cast<const float4*>(p + 4);
    float s = ((lo.x + lo.y) + (lo.z + lo.w)) + ((hi.x + hi.y) + (hi.z + hi.w));
    a[k] = wred(s);
  }
  if (lane == 0) {
    float npos = fmaxf(a[4], 1.0f);
    float negc = fmaxf(a[5], 1.0f);
    out[0] = a[0] / npos + a[3] / negc + a[1] / npos + a[2] / ((float)Bn * npos);
  }
}

extern "C" void kernel_launch(void* const* d_in, const int* in_sizes, int n_in,
                              void* d_out, int out_size, void* d_ws, size_t ws_size,
                              hipStream_t stream)
{
  const float* x  = (const float*)d_in[0];
  const float* tg = (const float*)d_in[1];
  float* part = (float*)d_ws;                     // 6*512 f32 = 12 KB

  k_batch<<<Bn, 256, 0, stream>>>(x, tg, part);
  k_red<<<1, 64, 0, stream>>>(part, (float*)d_out);
}